// Round 3
// baseline (78.959 us; speedup 1.0000x reference)
//
#include <hip/hip_runtime.h>
#include <hip/hip_bf16.h>

// Problem constants (fixed by reference)
#define NB    2
#define HW    25600      // 160*160
#define WDIM  160
#define NSTG  9

// ---- DPP add (full-rate VALU, no LDS pipe) ----
template <int CTRL>
__device__ __forceinline__ float dpp_add(float v) {
    int moved = __builtin_amdgcn_update_dpp(0, __float_as_int(v), CTRL, 0xf, 0xf, true);
    return v + __int_as_float(moved);
}

// sum over each 8-lane group, broadcast to all 8 lanes — pure DPP, no ds_swizzle.
// xor1, xor2 make each quad uniform with its quad-sum; ROW_HALF_MIRROR (0x141,
// lane i <-> 7-i within each 8-lane half-row) then delivers the other quad's sum.
__device__ __forceinline__ float reduce8(float v) {
    v = dpp_add<0xB1>(v);    // quad_perm [1,0,3,2] : xor 1
    v = dpp_add<0x4E>(v);    // quad_perm [2,3,0,1] : xor 2
    v = dpp_add<0x141>(v);   // row_half_mirror     : cross-quad within 8
    return v;
}

// One fused kernel: head 1x1 conv (recomputed per gather position),
// rank-collapsed 9-stage iteration, tail 1x1 conv.
// Layout: 8 lanes per pixel, 4 channels per lane -> 8 pixels/wave.
__global__ __launch_bounds__(256) void fused_kernel(const float* __restrict__ x,
                                                    const float* __restrict__ head_w,
                                                    const float* __restrict__ tail_w,
                                                    const float* __restrict__ alphas,
                                                    const float* __restrict__ betas,
                                                    float* __restrict__ out) {
    int tid = blockIdx.x * 256 + threadIdx.x;
    int sub = threadIdx.x & 7;          // channel group: channels 4*sub .. 4*sub+3
    int pid = tid >> 3;                 // pixel id in [0, NB*HW)
    int b   = blockIdx.x / 800;         // 32 pixels/block -> 800 blocks per batch
    int s2  = pid - b * HW;

    // head weights for my 4 channels: head_w is [32][3], rows c0..c0+3 contiguous
    int c0 = sub * 4;
    float hw[4][3];
#pragma unroll
    for (int j = 0; j < 4; ++j)
#pragma unroll
        for (int ci = 0; ci < 3; ++ci)
            hw[j][ci] = head_w[(c0 + j) * 3 + ci];

    const float* xb = x + b * 3 * HW;

    // Gather X[k][j] through the torch-unfold+reshape scramble (channel-preserving),
    // computing the head conv on the fly for each of the 9 scrambled positions.
    float X[9][4];
    int g9  = s2 * 9;
    int kk0 = g9 / HW;
    int r0  = g9 - kk0 * HW;
    int h0  = r0 / WDIM;
    int w0  = r0 - h0 * WDIM;
#pragma unroll
    for (int k2 = 0; k2 < 9; ++k2) {
        int r    = r0 + k2;
        int wrap = (r >= HW);
        int wn   = w0 + k2;
        int cw   = (wn >= WDIM);
        int w_nw = wn - (cw ? WDIM : 0);
        int h_nw = h0 + cw;
        int h    = wrap ? 0 : h_nw;
        int w    = wrap ? (r - HW) : w_nw;
        int kk   = kk0 + wrap;          // 0..8
        int ki   = kk / 3;
        int kj   = kk - ki * 3;
        int hh   = min(max(h + ki - 1, 0), 159);
        int ww   = min(max(w + kj - 1, 0), 159);
        int p    = hh * WDIM + ww;
        float x0 = xb[p], x1 = xb[HW + p], x2 = xb[2 * HW + p];
#pragma unroll
        for (int j = 0; j < 4; ++j)
            X[k2][j] = fmaxf(hw[j][0] * x0 + hw[j][1] * x1 + hw[j][2] * x2, 0.f);
    }

    // init: u[c] = mean_k X ; v[k] = mean_c X
    float u[4];
#pragma unroll
    for (int j = 0; j < 4; ++j) {
        float a = X[0][j];
#pragma unroll
        for (int k = 1; k < 9; ++k) a += X[k][j];
        u[j] = a * (1.f / 9.f);
    }
    float v[9];
#pragma unroll
    for (int k = 0; k < 9; ++k) {
        float pr = (X[k][0] + X[k][1]) + (X[k][2] + X[k][3]);
        v[k] = reduce8(pr) * (1.f / 32.f);
    }

    // 9 stages (rank-collapsed: all 3 ranks provably identical)
#pragma unroll
    for (int i = 0; i < NSTG; ++i) {
        float beta  = betas[i];
        float alpha = alphas[i];
        float sp = (u[0] * u[0] + u[1] * u[1]) + (u[2] * u[2] + u[3] * u[3]);
        float s  = reduce8(sp);
        float vs = 1.f - 3.f * beta * s;
#pragma unroll
        for (int k = 0; k < 9; ++k) {
            float qp = (u[0] * X[k][0] + u[1] * X[k][1]) + (u[2] * X[k][2] + u[3] * X[k][3]);
            float q  = reduce8(qp);
            v[k] = v[k] * vs + beta * q;
        }
        float t = 0.f;
#pragma unroll
        for (int k = 0; k < 9; ++k) t += v[k] * v[k];
        float us = 1.f - 3.f * alpha * t;
#pragma unroll
        for (int j = 0; j < 4; ++j) {
            float m = 0.f;
#pragma unroll
            for (int k = 0; k < 9; ++k) m += X[k][j] * v[k];
            u[j] = u[j] * us + alpha * m;
        }
    }

    // epilogue: UVc[c] = 3*u[c]*v[center=4]; out[o] = relu(sum_c UVc * tail_w[o*32+c])
    float v4 = v[4];
    float uvc[4];
#pragma unroll
    for (int j = 0; j < 4; ++j) uvc[j] = 3.f * u[j] * v4;
    float o[3];
#pragma unroll
    for (int oo = 0; oo < 3; ++oo) {
        const float* tw = tail_w + oo * 32 + c0;
        float pr = (uvc[0] * tw[0] + uvc[1] * tw[1]) + (uvc[2] * tw[2] + uvc[3] * tw[3]);
        o[oo] = fmaxf(reduce8(pr), 0.f);
    }
    if (sub == 0) {
        float* op = out + b * 3 * HW + s2;
        op[0]      = o[0];
        op[HW]     = o[1];
        op[2 * HW] = o[2];
    }
}

extern "C" void kernel_launch(void* const* d_in, const int* in_sizes, int n_in,
                              void* d_out, int out_size, void* d_ws, size_t ws_size,
                              hipStream_t stream) {
    const float* x      = (const float*)d_in[0];
    const float* head_w = (const float*)d_in[1];
    const float* tail_w = (const float*)d_in[2];
    const float* alphas = (const float*)d_in[3];
    const float* betas  = (const float*)d_in[4];
    float*       out    = (float*)d_out;

    // NB*HW pixels * 8 lanes/pixel = 409600 threads -> 1600 blocks of 256
    fused_kernel<<<dim3(NB * HW * 8 / 256), dim3(256), 0, stream>>>(
        x, head_w, tail_w, alphas, betas, out);
}

// Round 4
// 75.836 us; speedup vs baseline: 1.0412x; 1.0412x over previous
//
#include <hip/hip_runtime.h>
#include <hip/hip_bf16.h>

// Problem constants (fixed by reference)
#define NB    2
#define HW    25600      // 160*160
#define WDIM  160
#define NSTG  9

// ---- DPP add (full-rate VALU, no LDS pipe) ----
template <int CTRL>
__device__ __forceinline__ float dpp_add(float v) {
    int moved = __builtin_amdgcn_update_dpp(0, __float_as_int(v), CTRL, 0xf, 0xf, true);
    return v + __int_as_float(moved);
}

// sum over each 4-lane quad, broadcast to all 4 lanes — 2 quad_perm DPP adds.
__device__ __forceinline__ float reduce4(float v) {
    v = dpp_add<0xB1>(v);    // quad_perm [1,0,3,2] : xor 1
    v = dpp_add<0x4E>(v);    // quad_perm [2,3,0,1] : xor 2
    return v;
}

// One fused kernel: head 1x1 conv (recomputed per gather position),
// rank-collapsed 9-stage iteration, tail 1x1 conv.
// Layout: 4 lanes per pixel, 8 channels per lane -> 16 pixels/wave.
__global__ __launch_bounds__(256, 3) void fused_kernel(const float* __restrict__ x,
                                                       const float* __restrict__ head_w,
                                                       const float* __restrict__ tail_w,
                                                       const float* __restrict__ alphas,
                                                       const float* __restrict__ betas,
                                                       float* __restrict__ out) {
    int sub = threadIdx.x & 3;               // channel octet: channels 8*sub .. 8*sub+7
    int pid = blockIdx.x * 64 + (threadIdx.x >> 2);   // 64 pixels/block
    int b   = blockIdx.x / 400;              // 400 blocks per batch image
    int s2  = pid - b * HW;

    // head weights for my 8 channels: head_w is [32][3]
    int c0 = sub * 8;
    float hw[8][3];
#pragma unroll
    for (int j = 0; j < 8; ++j)
#pragma unroll
        for (int ci = 0; ci < 3; ++ci)
            hw[j][ci] = head_w[(c0 + j) * 3 + ci];

    const float* xb0 = x + b * 3 * HW;
    const float* xb1 = xb0 + HW;
    const float* xb2 = xb1 + HW;

    // Unfold+reshape scramble (channel-preserving): for pixel s2, g = s2*9+k2,
    // kk = g/HW (constant per pixel except at most one wrap), l = g%HW.
    // Precompute the two candidate kernel offsets (dh,dw) for kk0 and kk0+1.
    int g9  = s2 * 9;
    int kk0 = g9 / HW;
    int r0  = g9 - kk0 * HW;
    int h0  = r0 / WDIM;
    int w0  = r0 - h0 * WDIM;
    int ki0 = kk0 / 3;
    int dh0 = ki0 - 1,            dw0 = kk0 - ki0 * 3 - 1;
    int kk1 = kk0 + 1;
    int ki1 = kk1 / 3;
    int dh1 = ki1 - 1,            dw1 = kk1 - ki1 * 3 - 1;

    float X[9][8];
#pragma unroll
    for (int k2 = 0; k2 < 9; ++k2) {
        int r  = r0 + k2;
        int wn = w0 + k2;
        int cw = (wn >= WDIM);
        int w1 = cw ? wn - WDIM : wn;
        int h1 = h0 + cw;
        bool wr = (r >= HW);
        int h  = wr ? 0 : h1;
        int w  = wr ? r - HW : w1;
        int dh = wr ? dh1 : dh0;
        int dw = wr ? dw1 : dw0;
        int hh = min(max(h + dh, 0), 159);
        int ww = min(max(w + dw, 0), 159);
        int p  = hh * WDIM + ww;
        float x0 = xb0[p], x1 = xb1[p], x2 = xb2[p];
#pragma unroll
        for (int j = 0; j < 8; ++j)
            X[k2][j] = fmaxf(hw[j][0] * x0 + hw[j][1] * x1 + hw[j][2] * x2, 0.f);
    }

    // init: u[c] = mean_k X ; v[k] = mean_c X
    float u[8];
#pragma unroll
    for (int j = 0; j < 8; ++j) {
        float a = X[0][j];
#pragma unroll
        for (int k = 1; k < 9; ++k) a += X[k][j];
        u[j] = a * (1.f / 9.f);
    }
    float v[9];
#pragma unroll
    for (int k = 0; k < 9; ++k) {
        float pr = ((X[k][0] + X[k][1]) + (X[k][2] + X[k][3]))
                 + ((X[k][4] + X[k][5]) + (X[k][6] + X[k][7]));
        v[k] = reduce4(pr) * (1.f / 32.f);
    }

    // 9 stages (rank-collapsed: all 3 ranks provably identical)
#pragma unroll
    for (int i = 0; i < NSTG; ++i) {
        float b3 = 3.f * betas[i];
        float a3 = 3.f * alphas[i];
        float beta  = betas[i];
        float alpha = alphas[i];
        float sp = ((u[0] * u[0] + u[1] * u[1]) + (u[2] * u[2] + u[3] * u[3]))
                 + ((u[4] * u[4] + u[5] * u[5]) + (u[6] * u[6] + u[7] * u[7]));
        float s  = reduce4(sp);
        float vs = 1.f - b3 * s;
#pragma unroll
        for (int k = 0; k < 9; ++k) {
            float qp = u[0] * X[k][0];
#pragma unroll
            for (int j = 1; j < 8; ++j) qp += u[j] * X[k][j];
            float q = reduce4(qp);
            v[k] = v[k] * vs + beta * q;
        }
        // t: tree-associated (shortens the one serial chain on the critical path)
        float t = (((v[0] * v[0] + v[1] * v[1]) + (v[2] * v[2] + v[3] * v[3]))
                +  ((v[4] * v[4] + v[5] * v[5]) + (v[6] * v[6] + v[7] * v[7])))
                +  v[8] * v[8];
        float us = 1.f - a3 * t;
#pragma unroll
        for (int j = 0; j < 8; ++j) {
            float m = X[0][j] * v[0];
#pragma unroll
            for (int k = 1; k < 9; ++k) m += X[k][j] * v[k];
            u[j] = u[j] * us + alpha * m;
        }
    }

    // epilogue: UVc[c] = 3*u[c]*v[center=4]; out[o] = relu(sum_c UVc * tail_w[o*32+c])
    float v4 = v[4];
    float uvc[8];
#pragma unroll
    for (int j = 0; j < 8; ++j) uvc[j] = 3.f * u[j] * v4;
    float o[3];
#pragma unroll
    for (int oo = 0; oo < 3; ++oo) {
        const float* tw = tail_w + oo * 32 + c0;
        float pr = ((uvc[0] * tw[0] + uvc[1] * tw[1]) + (uvc[2] * tw[2] + uvc[3] * tw[3]))
                 + ((uvc[4] * tw[4] + uvc[5] * tw[5]) + (uvc[6] * tw[6] + uvc[7] * tw[7]));
        o[oo] = fmaxf(reduce4(pr), 0.f);
    }
    if (sub == 0) {
        float* op = out + b * 3 * HW + s2;
        op[0]      = o[0];
        op[HW]     = o[1];
        op[2 * HW] = o[2];
    }
}

extern "C" void kernel_launch(void* const* d_in, const int* in_sizes, int n_in,
                              void* d_out, int out_size, void* d_ws, size_t ws_size,
                              hipStream_t stream) {
    const float* x      = (const float*)d_in[0];
    const float* head_w = (const float*)d_in[1];
    const float* tail_w = (const float*)d_in[2];
    const float* alphas = (const float*)d_in[3];
    const float* betas  = (const float*)d_in[4];
    float*       out    = (float*)d_out;

    // NB*HW pixels * 4 lanes/pixel = 204800 threads -> 800 blocks of 256
    fused_kernel<<<dim3(NB * HW * 4 / 256), dim3(256), 0, stream>>>(
        x, head_w, tail_w, alphas, betas, out);
}